// Round 4
// baseline (915.746 us; speedup 1.0000x reference)
//
#include <hip/hip_runtime.h>
#include <hip/hip_bf16.h>
#include <math.h>

// Problem constants (AttentionPool): B=8, N=4096, C=1536, H=24, hd=64, R=8
#define Bb 8
#define Nn 4096
#define Cc 1536
#define Hh 24
#define HD 64
#define RR 8
#define MKV (Bb * Nn)        // 32768 rows for K/V GEMM
#define NKV (2 * Cc)         // 3072 cols (K and V fused)
#define NCHUNK 16            // key chunks for split attention
#define CK 256               // keys per chunk

typedef unsigned short u16;
typedef unsigned int u32;
typedef __attribute__((ext_vector_type(2))) u32 u32x2;

typedef __attribute__((ext_vector_type(8))) short bf16x8;
typedef __attribute__((ext_vector_type(4))) float f32x4;

__device__ __forceinline__ u16 f32_to_bf16(float f) {
    union { float f; u32 u; } v; v.f = f;
    u32 r = v.u + 0x7fffu + ((v.u >> 16) & 1u);  // RNE
    return (u16)(r >> 16);
}
__device__ __forceinline__ float bflo(u32 p) {
    union { u32 u; float f; } v; v.u = p << 16; return v.f;
}
__device__ __forceinline__ float bfhi(u32 p) {
    union { u32 u; float f; } v; v.u = p & 0xffff0000u; return v.f;
}
__device__ __forceinline__ ushort4 cvt4(float4 v) {
    ushort4 o;
    o.x = f32_to_bf16(v.x); o.y = f32_to_bf16(v.y);
    o.z = f32_to_bf16(v.z); o.w = f32_to_bf16(v.w);
    return o;
}

// ---- packed f32x2 -> bf16x2 for GEMM A staging (gfx950 v_cvt_pk_bf16_f32) ----
#if __has_builtin(__builtin_amdgcn_cvt_pk_bf16_f32)
typedef __attribute__((ext_vector_type(2))) __bf16 bf16x2_t;
__device__ __forceinline__ u32 cvt_pk(float a, float b) {
    union { bf16x2_t v; u32 u; } x;
    x.v = __builtin_amdgcn_cvt_pk_bf16_f32(a, b);
    return x.u;
}
#else
__device__ __forceinline__ u32 cvt_pk(float a, float b) {
    u32 ua = __builtin_bit_cast(u32, a) + 0x8000u;   // round-half-up (inputs finite)
    u32 ub = __builtin_bit_cast(u32, b) + 0x8000u;
    return __builtin_amdgcn_perm(ub, ua, 0x07060302u);  // {ua[31:16], ub[31:16]}
}
#endif
__device__ __forceinline__ bf16x8 cvt8(f32x4 lo, f32x4 hi) {
    union { bf16x8 v; u32 w[4]; } o;
    o.w[0] = cvt_pk(lo.x, lo.y); o.w[1] = cvt_pk(lo.z, lo.w);
    o.w[2] = cvt_pk(hi.x, hi.y); o.w[3] = cvt_pk(hi.z, hi.w);
    return o.v;
}

// ---------------- fused prep: weight casts + q gather + zero fills ----------------
// sections (blocks): [0,9216) 4 weight casts | [9216,9312) q gather (f32, *0.125)
//   [9312,9408) zero xqp rows 64..127 | [9408,9600) zero aob | [9600,9696) zero d_out
__global__ __launch_bounds__(256)
void prep_kernel(const float* __restrict__ x,
                 const float* __restrict__ Wk, const float* __restrict__ Wv,
                 const float* __restrict__ Wq, const float* __restrict__ Wp,
                 u16* __restrict__ wkvb, u16* __restrict__ wqb, u16* __restrict__ wpb,
                 float* __restrict__ xqp, float* __restrict__ aob,
                 float* __restrict__ dout)
{
    const int blk = blockIdx.x, tid = threadIdx.x;
    if (blk < 9216) {
        int w = blk / 2304;
        int i = (blk - w * 2304) * 256 + tid;        // < 589824 quads
        const float4* src = (w == 0) ? (const float4*)Wk : (w == 1) ? (const float4*)Wv
                          : (w == 2) ? (const float4*)Wq : (const float4*)Wp;
        u16* dst = (w == 0) ? wkvb : (w == 1) ? wkvb + 2359296 : (w == 2) ? wqb : wpb;
        ((ushort4*)dst)[i] = cvt4(src[i]);
    } else if (blk < 9312) {                         // q gather: 24576 float4s
        int i = (blk - 9216) * 256 + tid;
        int m = i / 384, c4 = i - m * 384;           // m = b*8+r
        int b = m >> 3, r = m & 7;
        float4 v = ((const float4*)x)[(size_t)(b * Nn + r) * 384 + c4];
        float4 o = {v.x * 0.125f, v.y * 0.125f, v.z * 0.125f, v.w * 0.125f};
        ((float4*)xqp)[i] = o;
    } else if (blk < 9408) {                         // zero xqp rows 64..127
        int i = (blk - 9312) * 256 + tid;
        float4 z = {0.f, 0.f, 0.f, 0.f};
        ((float4*)(xqp + 64 * Cc))[i] = z;
    } else if (blk < 9600) {                         // zero aob (128 rows f32)
        int i = (blk - 9408) * 256 + tid;
        float4 z = {0.f, 0.f, 0.f, 0.f};
        ((float4*)aob)[i] = z;
    } else {                                         // zero d_out (split-K atomics)
        int i = (blk - 9600) * 256 + tid;
        float4 z = {0.f, 0.f, 0.f, 0.f};
        ((float4*)dout)[i] = z;
    }
}

// ---------------- GEMM body: A is f32 (staged to LDS, cvt on fragment read) ----------------
// C[M,N] = bf16(A[M,K]) * B[N,K]^T.  A LDS row = 64 f32 (256 B) = 16 chunks of 16 B,
// chunk c16 of row r stored at c16 ^ ((r&7)<<1)  (adjacent pairs stay adjacent).
// B LDS row = 64 bf16 (128 B) = 8 chunks, chunk c at c ^ (r&7)  (round-3, 0 conflicts).
// OUT: 0 = f32 store, 1 = bf16 store, 2 = f32 atomicAdd (split-K)
template <int OUT>
__device__ __forceinline__ void gemm_body_f32A(
    const float* __restrict__ A, const u16* __restrict__ B, void* __restrict__ Cv,
    const float* __restrict__ bias, int M_valid, int N, int K,
    int m0, int n0, int kbeg, int kend, float* Asf, u16* Bs)
{
    const int tid = threadIdx.x;
    const int wave = tid >> 6, lane = tid & 63;
    const int wm = (wave & 1) * 64, wn = (wave >> 1) * 64;
    const int fm = lane & 15;
    const int kq = lane >> 4;            // 0..3

    f32x4 acc[4][4] = {};

    // A staging: 8 DMA sets; e = tid*4 + off*1024 f32 elems; r=e>>6, c16=(e>>2)&15
    const float* aptr[8]; int aoff[8];
    #pragma unroll
    for (int off = 0; off < 8; ++off) {
        int e = tid * 4 + off * 1024;
        int r = e >> 6, c16 = (e >> 2) & 15;
        int cs = c16 ^ ((r & 7) << 1);
        aptr[off] = A + (size_t)(m0 + r) * K + cs * 4;
        aoff[off] = e;
    }
    // B staging: 4 DMA sets (bf16)
    const u16* bptr[4]; int boff[4];
    #pragma unroll
    for (int off = 0; off < 4; ++off) {
        int e = tid * 8 + off * 2048;
        int r = e >> 6, cp = (e >> 3) & 7;
        int csrc = cp ^ (r & 7);
        bptr[off] = B + (size_t)(n0 + r) * K + csrc * 8;
        boff[off] = e;
    }

    for (int k0 = kbeg; k0 < kend; k0 += 64) {
        #pragma unroll
        for (int off = 0; off < 8; ++off)
            __builtin_amdgcn_global_load_lds(
                (const __attribute__((address_space(1))) void*)(aptr[off] + k0),
                (__attribute__((address_space(3))) void*)(Asf + aoff[off]), 16, 0, 0);
        #pragma unroll
        for (int off = 0; off < 4; ++off)
            __builtin_amdgcn_global_load_lds(
                (const __attribute__((address_space(1))) void*)(bptr[off] + k0),
                (__attribute__((address_space(3))) void*)(Bs + boff[off]), 16, 0, 0);
        __syncthreads();

        #pragma unroll
        for (int ks = 0; ks < 2; ++ks) {
            bf16x8 af[4], bfr[4];
            #pragma unroll
            for (int i = 0; i < 4; ++i) {
                int r = wm + i * 16 + fm;
                int m = ks * 4 + kq;
                int cp8 = (m ^ (r & 7)) << 3;    // f32 index of the 8-f32 group
                f32x4 lo = *(const f32x4*)&Asf[r * 64 + cp8];
                f32x4 hi = *(const f32x4*)&Asf[r * 64 + cp8 + 4];
                af[i] = cvt8(lo, hi);
            }
            #pragma unroll
            for (int j = 0; j < 4; ++j) {
                int r = wn + j * 16 + fm;
                int c = ks * 4 + kq;
                bfr[j] = *(const bf16x8*)&Bs[r * 64 + ((c ^ (r & 7)) << 3)];
            }
            #pragma unroll
            for (int i = 0; i < 4; ++i)
                #pragma unroll
                for (int j = 0; j < 4; ++j)
                    acc[i][j] = __builtin_amdgcn_mfma_f32_16x16x32_bf16(af[i], bfr[j], acc[i][j], 0, 0, 0);
        }
        __syncthreads();
    }

    // C/D layout: col = lane&15, row = (lane>>4)*4 + reg  [m89, verified]
    const int col = lane & 15, rb = (lane >> 4) * 4;
    #pragma unroll
    for (int i = 0; i < 4; ++i)
        #pragma unroll
        for (int j = 0; j < 4; ++j)
            #pragma unroll
            for (int rg = 0; rg < 4; ++rg) {
                int m = m0 + wm + i * 16 + rb + rg;
                if (m < M_valid) {
                    int n = n0 + wn + j * 16 + col;
                    float v = acc[i][j][rg];
                    if (bias) v += bias[n];
                    size_t idx = (size_t)m * N + n;
                    if (OUT == 0)       ((float*)Cv)[idx] = v;
                    else if (OUT == 1)  ((u16*)Cv)[idx] = f32_to_bf16(v);
                    else                atomicAdd((float*)Cv + idx, v);
                }
            }
}

// ---------------- merged dispatch: blocks 0..11 = q proj; 12..6155 = KV proj ----------------
__global__ __launch_bounds__(256, 3)
void gemm_main(const float* __restrict__ xqp, const u16* __restrict__ wqb,
               float* __restrict__ qout,
               const float* __restrict__ x, const u16* __restrict__ wkvb,
               u16* __restrict__ kvb)
{
    __shared__ float Asf[128 * 64];   // 32 KB
    __shared__ u16   Bs[128 * 64];    // 16 KB
    const int blk = blockIdx.x;
    if (blk < 12) {
        gemm_body_f32A<0>(xqp, wqb, qout, nullptr, 128, Cc, Cc, 0, blk * 128, 0, Cc, Asf, Bs);
    } else {
        int u = blk - 12;
        int g = u & 7, s = u >> 3;               // 768 blocks per XCD class
        int mb = g * 32 + s / 24, nb = s % 24;
        gemm_body_f32A<1>(x, wkvb, kvb, nullptr, MKV, NKV, Cc, mb * 128, nb * 128, 0, Cc, Asf, Bs);
    }
}

// ---------------- output projection, split-K x4 with f32 atomics ----------------
__global__ __launch_bounds__(256, 3)
void gemm_out(const float* __restrict__ aob, const u16* __restrict__ wpb,
              float* __restrict__ out, const float* __restrict__ bp)
{
    __shared__ float Asf[128 * 64];
    __shared__ u16   Bs[128 * 64];
    const int nb = blockIdx.x;                   // 0..11
    const int z = blockIdx.y;                    // 0..3
    gemm_body_f32A<2>(aob, wpb, out, (z == 0) ? bp : nullptr,
                      64, Cc, Cc, 0, nb * 128, z * 384, (z + 1) * 384, Asf, Bs);
}

// ---------------- split attention: grid (NCHUNK, B*H), 256 keys per block ----------------
__global__ __launch_bounds__(256)
void attn_part_kernel(const float* __restrict__ qout, const u16* __restrict__ kv,
                      const int* __restrict__ mask,
                      float* __restrict__ opart, float* __restrict__ mstat,
                      float* __restrict__ lstat)
{
    const int chunk = blockIdx.x;       // 0..15
    const int bh = blockIdx.y;          // 0..191
    const int b = bh / Hh, h = bh - b * Hh;
    const int tid = threadIdx.x;

    __shared__ u16  Vs[CK * HD];        // 32 KB
    __shared__ float Ps[RR][CK];        // 8 KB
    __shared__ float qs[RR * HD];       // 2 KB

    for (int i = tid; i < RR * HD; i += 256)
        qs[i] = qout[(size_t)(b * RR + (i >> 6)) * Cc + h * HD + (i & 63)];
    __syncthreads();

    // V-chunk DMA (overlaps QK^T; drained by the next barrier)
    {
        const u16* vsrc = kv + (size_t)(b * Nn + chunk * CK) * NKV + Cc + h * HD;
        const int vr = tid >> 3, vc = (tid & 7) * 8;
        #pragma unroll
        for (int i = 0; i < 8; ++i) {
            __builtin_amdgcn_global_load_lds(
                (const __attribute__((address_space(1))) void*)(vsrc + (size_t)(i * 32 + vr) * NKV + vc),
                (__attribute__((address_space(3))) void*)(Vs + i * 2048 + tid * 8), 16, 0, 0);
        }
    }

    // phase A: thread = key; masked scores
    {
        const int j = chunk * CK + tid;
        float s[RR] = {0, 0, 0, 0, 0, 0, 0, 0};
        const u16* krow = kv + (size_t)(b * Nn + j) * NKV + h * HD;
        #pragma unroll
        for (int c = 0; c < 8; ++c) {
            uint4 kvec = *(const uint4*)(krow + c * 8);
            float kf0 = bflo(kvec.x), kf1 = bfhi(kvec.x);
            float kf2 = bflo(kvec.y), kf3 = bfhi(kvec.y);
            float kf4 = bflo(kvec.z), kf5 = bfhi(kvec.z);
            float kf6 = bflo(kvec.w), kf7 = bfhi(kvec.w);
            #pragma unroll
            for (int r = 0; r < RR; ++r) {
                const float4 qa = *(const float4*)&qs[r * HD + c * 8];
                const float4 qb = *(const float4*)&qs[r * HD + c * 8 + 4];
                s[r] += qa.x * kf0 + qa.y * kf1 + qa.z * kf2 + qa.w * kf3
                      + qb.x * kf4 + qb.y * kf5 + qb.z * kf6 + qb.w * kf7;
            }
        }
        #pragma unroll
        for (int r = 0; r < RR; ++r) {
            bool keep = (j < RR) ? (j == r)
                                 : (mask[(size_t)(b * RR + r) * (Nn - RR) + (j - RR)] != 0);
            Ps[r][tid] = keep ? s[r] : -INFINITY;
        }
    }
    __syncthreads();

    // phase A2: per-row chunk max & exp-sum
    {
        const int r = tid >> 5, g = tid & 31;
        float vals[CK / 32];
        float mx = -INFINITY;
        #pragma unroll
        for (int i = 0; i < CK / 32; ++i) {
            vals[i] = Ps[r][g + 32 * i];
            mx = fmaxf(mx, vals[i]);
        }
        #pragma unroll
        for (int m = 16; m >= 1; m >>= 1) mx = fmaxf(mx, __shfl_xor(mx, m));
        const float mfin = fmaxf(mx, -1e30f);
        float sum = 0.f;
        #pragma unroll
        for (int i = 0; i < CK / 32; ++i) {
            float e = __expf(vals[i] - mfin);
            Ps[r][g + 32 * i] = e;
            sum += e;
        }
        #pragma unroll
        for (int m = 16; m >= 1; m >>= 1) sum += __shfl_xor(sum, m);
        if (g == 0) {
            size_t si = ((size_t)bh * NCHUNK + chunk) * RR + r;
            mstat[si] = mx;
            lstat[si] = sum;
        }
    }
    __syncthreads();

    // phase B: o[r,d] = sum_k P[r,k] * V[k,d]; 16 lanes x 4 dims, k split over 2 half-groups
    {
        const int r  = tid >> 5;
        const int g  = tid & 31;
        const int kh = g >> 4;               // 0/1 -> keys [kh*128, kh*128+128)
        const int d4 = (g & 15) * 4;
        float a0 = 0.f, a1 = 0.f, a2 = 0.f, a3 = 0.f;
        const float* pr = &Ps[r][kh * 128];
        const u16* vb = Vs + kh * 128 * HD + d4;
        #pragma unroll 2
        for (int k4 = 0; k4 < 32; ++k4) {
            f32x4 pv = *(const f32x4*)(pr + k4 * 4);
            #pragma unroll
            for (int t = 0; t < 4; ++t) {
                float p = pv[t];
                u32x2 vv = *(const u32x2*)(vb + (k4 * 4 + t) * HD);
                a0 += p * bflo(vv.x); a1 += p * bfhi(vv.x);
                a2 += p * bflo(vv.y); a3 += p * bfhi(vv.y);
            }
        }
        a0 += __shfl_xor(a0, 16); a1 += __shfl_xor(a1, 16);
        a2 += __shfl_xor(a2, 16); a3 += __shfl_xor(a3, 16);
        if (kh == 0) {
            size_t po = ((size_t)bh * NCHUNK + chunk) * (RR * HD) + r * HD + d4;
            float4 o = {a0, a1, a2, a3};
            *(float4*)(opart + po) = o;
        }
    }
}

// ---------------- combine partials -> f32 attention output ----------------
__global__ __launch_bounds__(256)
void attn_combine_kernel(const float* __restrict__ opart, const float* __restrict__ mstat,
                         const float* __restrict__ lstat, float* __restrict__ aob)
{
    int idx = blockIdx.x * 256 + threadIdx.x;   // < 64*1536
    int row = idx / Cc, col = idx - row * Cc;
    int b = row >> 3, r = row & 7;
    int h = col >> 6, d = col & 63;
    int bh = b * Hh + h;
    float M = -INFINITY;
    #pragma unroll
    for (int c = 0; c < NCHUNK; ++c)
        M = fmaxf(M, mstat[((size_t)bh * NCHUNK + c) * RR + r]);
    float L = 0.f, O = 0.f;
    #pragma unroll
    for (int c = 0; c < NCHUNK; ++c) {
        size_t si = ((size_t)bh * NCHUNK + c) * RR + r;
        float w = __expf(mstat[si] - M);
        L += w * lstat[si];
        O += w * opart[((size_t)bh * NCHUNK + c) * (RR * HD) + r * HD + d];
    }
    aob[(size_t)row * Cc + col] = O / L;
}

// ---------------- launch ----------------
extern "C" void kernel_launch(void* const* d_in, const int* in_sizes, int n_in,
                              void* d_out, int out_size, void* d_ws, size_t ws_size,
                              hipStream_t stream)
{
    const float* x    = (const float*)d_in[0];
    const int*   mask = (const int*)d_in[1];
    const float* Wq   = (const float*)d_in[2];
    const float* Wk   = (const float*)d_in[3];
    const float* Wv   = (const float*)d_in[4];
    const float* Wp   = (const float*)d_in[5];
    const float* bp   = (const float*)d_in[6];

    char* ws = (char*)d_ws;
    u16*   wkvb  = (u16*)(ws);                        //   9,437,184  [Wk;Wv] bf16 [3072,1536]
    u16*   wqb   = (u16*)(ws + 9437184);              //   4,718,592  Wq bf16
    u16*   wpb   = (u16*)(ws + 14155776);             //   4,718,592  Wp bf16
    u16*   kvb   = (u16*)(ws + 18874368);             // 201,326,592  kv bf16 [32768,3072]
    float* xqp   = (float*)(ws + 220200960);          //     786,432  q input padded [128,1536] f32
    float* qout  = (float*)(ws + 220987392);          //     786,432  q proj f32 [128,1536]
    float* aob   = (float*)(ws + 221773824);          //     786,432  attn out padded [128,1536] f32
    float* opart = (float*)(ws + 222560256);          //   6,291,456  [192][16][8][64] f32
    float* mstat = (float*)(ws + 228851712);          //      98,304
    float* lstat = (float*)(ws + 228950016);          //      98,304

    // 1: weight casts + q gather + zero fills
    prep_kernel<<<9696, 256, 0, stream>>>(x, Wk, Wv, Wq, Wp, wkvb, wqb, wpb,
                                          xqp, aob, (float*)d_out);
    // 2: q proj (blocks 0..11, A=xqp f32) + fused K/V proj (blocks 12..6155, A=x f32)
    gemm_main<<<6156, 256, 0, stream>>>(xqp, wqb, qout, x, wkvb, kvb);
    // 3: split attention
    attn_part_kernel<<<dim3(NCHUNK, Bb * Hh), 256, 0, stream>>>(qout, kvb, mask,
                                                                opart, mstat, lstat);
    // 4: combine (f32 out)
    attn_combine_kernel<<<384, 256, 0, stream>>>(opart, mstat, lstat, aob);
    // 5: output projection, split-K atomics (d_out zeroed by prep)
    gemm_out<<<dim3(12, 4), 256, 0, stream>>>(aob, wpb, (float*)d_out, bp);
}

// Round 5
// 913.160 us; speedup vs baseline: 1.0028x; 1.0028x over previous
//
#include <hip/hip_runtime.h>
#include <hip/hip_bf16.h>
#include <math.h>

// Problem constants (AttentionPool): B=8, N=4096, C=1536, H=24, hd=64, R=8
#define Bb 8
#define Nn 4096
#define Cc 1536
#define Hh 24
#define HD 64
#define RR 8
#define MKV (Bb * Nn)        // 32768 rows for K/V GEMM
#define NKV (2 * Cc)         // 3072 cols (K and V fused)
#define NCHUNK 16            // key chunks for split attention
#define CK 256               // keys per chunk

typedef unsigned short u16;
typedef unsigned int u32;
typedef __attribute__((ext_vector_type(2))) u32 u32x2;

typedef __attribute__((ext_vector_type(8))) short bf16x8;
typedef __attribute__((ext_vector_type(4))) float f32x4;

__device__ __forceinline__ u16 f32_to_bf16(float f) {
    union { float f; u32 u; } v; v.f = f;
    u32 r = v.u + 0x7fffu + ((v.u >> 16) & 1u);  // RNE
    return (u16)(r >> 16);
}
__device__ __forceinline__ float bflo(u32 p) {
    union { u32 u; float f; } v; v.u = p << 16; return v.f;
}
__device__ __forceinline__ float bfhi(u32 p) {
    union { u32 u; float f; } v; v.u = p & 0xffff0000u; return v.f;
}
__device__ __forceinline__ ushort4 cvt4(float4 v) {
    ushort4 o;
    o.x = f32_to_bf16(v.x); o.y = f32_to_bf16(v.y);
    o.z = f32_to_bf16(v.z); o.w = f32_to_bf16(v.w);
    return o;
}

// ---- packed f32x2 -> bf16x2 for GEMM A staging (gfx950 v_cvt_pk_bf16_f32) ----
#if __has_builtin(__builtin_amdgcn_cvt_pk_bf16_f32)
typedef __attribute__((ext_vector_type(2))) __bf16 bf16x2_t;
__device__ __forceinline__ u32 cvt_pk(float a, float b) {
    union { bf16x2_t v; u32 u; } x;
    x.v = __builtin_amdgcn_cvt_pk_bf16_f32(a, b);
    return x.u;
}
#else
__device__ __forceinline__ u32 cvt_pk(float a, float b) {
    u32 ua = __builtin_bit_cast(u32, a) + 0x8000u;   // round-half-up (inputs finite)
    u32 ub = __builtin_bit_cast(u32, b) + 0x8000u;
    return __builtin_amdgcn_perm(ub, ua, 0x07060302u);  // {ua[31:16], ub[31:16]}
}
#endif
__device__ __forceinline__ bf16x8 cvt8(f32x4 lo, f32x4 hi) {
    union { bf16x8 v; u32 w[4]; } o;
    o.w[0] = cvt_pk(lo.x, lo.y); o.w[1] = cvt_pk(lo.z, lo.w);
    o.w[2] = cvt_pk(hi.x, hi.y); o.w[3] = cvt_pk(hi.z, hi.w);
    return o.v;
}

// ---------------- fused prep: weight casts + q gather + zero fills ----------------
// sections (blocks): [0,9216) 4 weight casts | [9216,9312) q gather (f32, *0.125)
//   [9312,9408) zero xqp rows 64..127 | [9408,9600) zero aob | [9600,9696) zero d_out
__global__ __launch_bounds__(256)
void prep_kernel(const float* __restrict__ x,
                 const float* __restrict__ Wk, const float* __restrict__ Wv,
                 const float* __restrict__ Wq, const float* __restrict__ Wp,
                 u16* __restrict__ wkvb, u16* __restrict__ wqb, u16* __restrict__ wpb,
                 float* __restrict__ xqp, float* __restrict__ aob,
                 float* __restrict__ dout)
{
    const int blk = blockIdx.x, tid = threadIdx.x;
    if (blk < 9216) {
        int w = blk / 2304;
        int i = (blk - w * 2304) * 256 + tid;        // < 589824 quads
        const float4* src = (w == 0) ? (const float4*)Wk : (w == 1) ? (const float4*)Wv
                          : (w == 2) ? (const float4*)Wq : (const float4*)Wp;
        u16* dst = (w == 0) ? wkvb : (w == 1) ? wkvb + 2359296 : (w == 2) ? wqb : wpb;
        ((ushort4*)dst)[i] = cvt4(src[i]);
    } else if (blk < 9312) {                         // q gather: 24576 float4s
        int i = (blk - 9216) * 256 + tid;
        int m = i / 384, c4 = i - m * 384;           // m = b*8+r
        int b = m >> 3, r = m & 7;
        float4 v = ((const float4*)x)[(size_t)(b * Nn + r) * 384 + c4];
        float4 o = {v.x * 0.125f, v.y * 0.125f, v.z * 0.125f, v.w * 0.125f};
        ((float4*)xqp)[i] = o;
    } else if (blk < 9408) {                         // zero xqp rows 64..127
        int i = (blk - 9312) * 256 + tid;
        float4 z = {0.f, 0.f, 0.f, 0.f};
        ((float4*)(xqp + 64 * Cc))[i] = z;
    } else if (blk < 9600) {                         // zero aob (128 rows f32)
        int i = (blk - 9408) * 256 + tid;
        float4 z = {0.f, 0.f, 0.f, 0.f};
        ((float4*)aob)[i] = z;
    } else {                                         // zero d_out (split-K atomics)
        int i = (blk - 9600) * 256 + tid;
        float4 z = {0.f, 0.f, 0.f, 0.f};
        ((float4*)dout)[i] = z;
    }
}

// ---------------- GEMM body: A is f32 (staged to LDS, cvt on fragment read) ----------------
// C[M,N] = bf16(A[M,K]) * B[N,K]^T.
// A LDS row = 64 f32 (256 B) = 16 chunks of 16 B; source chunk c stored at c ^ (r&7).
//   Read: k-group m (8 f32) = source chunks {2m,2m+1} -> LDS positions {(2m)^t,(2m+1)^t},
//   t=r&7. Bank-quad (2m^t)&7 is a bijection over t in 0..7 -> all 8 quads covered,
//   2 lanes/quad (fm,fm+8) = free 2-way. (Round-4 sigma=(r&7)<<1 hit only even quads
//   -> 4-way conflicts, 3.78e7 SQ_LDS_BANK_CONFLICT. This fixes that.)
// B LDS row = 64 bf16 (128 B) = 8 chunks, chunk c at c ^ (r&7)  (round-3, 0 conflicts).
// OUT: 0 = f32 store, 1 = bf16 store, 2 = f32 atomicAdd (split-K)
template <int OUT>
__device__ __forceinline__ void gemm_body_f32A(
    const float* __restrict__ A, const u16* __restrict__ B, void* __restrict__ Cv,
    const float* __restrict__ bias, int M_valid, int N, int K,
    int m0, int n0, int kbeg, int kend, float* Asf, u16* Bs)
{
    const int tid = threadIdx.x;
    const int wave = tid >> 6, lane = tid & 63;
    const int wm = (wave & 1) * 64, wn = (wave >> 1) * 64;
    const int fm = lane & 15;
    const int kq = lane >> 4;            // 0..3

    f32x4 acc[4][4] = {};

    // A staging: 8 DMA sets; LDS slot e = tid*4 + off*1024 f32; r=e>>6, pos=(e>>2)&15,
    // source chunk = pos ^ (r&7)
    const float* aptr[8]; int aoff[8];
    #pragma unroll
    for (int off = 0; off < 8; ++off) {
        int e = tid * 4 + off * 1024;
        int r = e >> 6, pos = (e >> 2) & 15;
        int cs = pos ^ (r & 7);
        aptr[off] = A + (size_t)(m0 + r) * K + cs * 4;
        aoff[off] = e;
    }
    // B staging: 4 DMA sets (bf16)
    const u16* bptr[4]; int boff[4];
    #pragma unroll
    for (int off = 0; off < 4; ++off) {
        int e = tid * 8 + off * 2048;
        int r = e >> 6, cp = (e >> 3) & 7;
        int csrc = cp ^ (r & 7);
        bptr[off] = B + (size_t)(n0 + r) * K + csrc * 8;
        boff[off] = e;
    }

    for (int k0 = kbeg; k0 < kend; k0 += 64) {
        #pragma unroll
        for (int off = 0; off < 8; ++off)
            __builtin_amdgcn_global_load_lds(
                (const __attribute__((address_space(1))) void*)(aptr[off] + k0),
                (__attribute__((address_space(3))) void*)(Asf + aoff[off]), 16, 0, 0);
        #pragma unroll
        for (int off = 0; off < 4; ++off)
            __builtin_amdgcn_global_load_lds(
                (const __attribute__((address_space(1))) void*)(bptr[off] + k0),
                (__attribute__((address_space(3))) void*)(Bs + boff[off]), 16, 0, 0);
        __syncthreads();

        #pragma unroll
        for (int ks = 0; ks < 2; ++ks) {
            bf16x8 af[4], bfr[4];
            #pragma unroll
            for (int i = 0; i < 4; ++i) {
                int r = wm + i * 16 + fm;
                int m = ks * 4 + kq;
                int t = r & 7;
                int p_lo = ((m << 1) ^ t) << 2;        // f32 idx of source chunk 2m
                int p_hi = (((m << 1) | 1) ^ t) << 2;  // f32 idx of source chunk 2m+1
                f32x4 lo = *(const f32x4*)&Asf[r * 64 + p_lo];
                f32x4 hi = *(const f32x4*)&Asf[r * 64 + p_hi];
                af[i] = cvt8(lo, hi);
            }
            #pragma unroll
            for (int j = 0; j < 4; ++j) {
                int r = wn + j * 16 + fm;
                int c = ks * 4 + kq;
                bfr[j] = *(const bf16x8*)&Bs[r * 64 + ((c ^ (r & 7)) << 3)];
            }
            #pragma unroll
            for (int i = 0; i < 4; ++i)
                #pragma unroll
                for (int j = 0; j < 4; ++j)
                    acc[i][j] = __builtin_amdgcn_mfma_f32_16x16x32_bf16(af[i], bfr[j], acc[i][j], 0, 0, 0);
        }
        __syncthreads();
    }

    // C/D layout: col = lane&15, row = (lane>>4)*4 + reg  [m89, verified]
    const int col = lane & 15, rb = (lane >> 4) * 4;
    #pragma unroll
    for (int i = 0; i < 4; ++i)
        #pragma unroll
        for (int j = 0; j < 4; ++j)
            #pragma unroll
            for (int rg = 0; rg < 4; ++rg) {
                int m = m0 + wm + i * 16 + rb + rg;
                if (m < M_valid) {
                    int n = n0 + wn + j * 16 + col;
                    float v = acc[i][j][rg];
                    if (bias) v += bias[n];
                    size_t idx = (size_t)m * N + n;
                    if (OUT == 0)       ((float*)Cv)[idx] = v;
                    else if (OUT == 1)  ((u16*)Cv)[idx] = f32_to_bf16(v);
                    else                atomicAdd((float*)Cv + idx, v);
                }
            }
}

// ---------------- merged dispatch: blocks 0..11 = q proj; 12..6155 = KV proj ----------------
__global__ __launch_bounds__(256, 3)
void gemm_main(const float* __restrict__ xqp, const u16* __restrict__ wqb,
               float* __restrict__ qout,
               const float* __restrict__ x, const u16* __restrict__ wkvb,
               u16* __restrict__ kvb)
{
    __shared__ float Asf[128 * 64];   // 32 KB
    __shared__ u16   Bs[128 * 64];    // 16 KB
    const int blk = blockIdx.x;
    if (blk < 12) {
        gemm_body_f32A<0>(xqp, wqb, qout, nullptr, 128, Cc, Cc, 0, blk * 128, 0, Cc, Asf, Bs);
    } else {
        int u = blk - 12;
        int g = u & 7, s = u >> 3;               // 768 blocks per XCD class
        int mb = g * 32 + s / 24, nb = s % 24;
        gemm_body_f32A<1>(x, wkvb, kvb, nullptr, MKV, NKV, Cc, mb * 128, nb * 128, 0, Cc, Asf, Bs);
    }
}

// ---------------- output projection, split-K x4 with f32 atomics ----------------
__global__ __launch_bounds__(256, 3)
void gemm_out(const float* __restrict__ aob, const u16* __restrict__ wpb,
              float* __restrict__ out, const float* __restrict__ bp)
{
    __shared__ float Asf[128 * 64];
    __shared__ u16   Bs[128 * 64];
    const int nb = blockIdx.x;                   // 0..11
    const int z = blockIdx.y;                    // 0..3
    gemm_body_f32A<2>(aob, wpb, out, (z == 0) ? bp : nullptr,
                      64, Cc, Cc, 0, nb * 128, z * 384, (z + 1) * 384, Asf, Bs);
}

// ---------------- split attention: grid (NCHUNK, B*H), 256 keys per block ----------------
__global__ __launch_bounds__(256)
void attn_part_kernel(const float* __restrict__ qout, const u16* __restrict__ kv,
                      const int* __restrict__ mask,
                      float* __restrict__ opart, float* __restrict__ mstat,
                      float* __restrict__ lstat)
{
    const int chunk = blockIdx.x;       // 0..15
    const int bh = blockIdx.y;          // 0..191
    const int b = bh / Hh, h = bh - b * Hh;
    const int tid = threadIdx.x;

    __shared__ u16  Vs[CK * HD];        // 32 KB
    __shared__ float Ps[RR][CK];        // 8 KB
    __shared__ float qs[RR * HD];       // 2 KB

    for (int i = tid; i < RR * HD; i += 256)
        qs[i] = qout[(size_t)(b * RR + (i >> 6)) * Cc + h * HD + (i & 63)];
    __syncthreads();

    // V-chunk DMA (overlaps QK^T; drained by the next barrier)
    {
        const u16* vsrc = kv + (size_t)(b * Nn + chunk * CK) * NKV + Cc + h * HD;
        const int vr = tid >> 3, vc = (tid & 7) * 8;
        #pragma unroll
        for (int i = 0; i < 8; ++i) {
            __builtin_amdgcn_global_load_lds(
                (const __attribute__((address_space(1))) void*)(vsrc + (size_t)(i * 32 + vr) * NKV + vc),
                (__attribute__((address_space(3))) void*)(Vs + i * 2048 + tid * 8), 16, 0, 0);
        }
    }

    // phase A: thread = key; masked scores
    {
        const int j = chunk * CK + tid;
        float s[RR] = {0, 0, 0, 0, 0, 0, 0, 0};
        const u16* krow = kv + (size_t)(b * Nn + j) * NKV + h * HD;
        #pragma unroll
        for (int c = 0; c < 8; ++c) {
            uint4 kvec = *(const uint4*)(krow + c * 8);
            float kf0 = bflo(kvec.x), kf1 = bfhi(kvec.x);
            float kf2 = bflo(kvec.y), kf3 = bfhi(kvec.y);
            float kf4 = bflo(kvec.z), kf5 = bfhi(kvec.z);
            float kf6 = bflo(kvec.w), kf7 = bfhi(kvec.w);
            #pragma unroll
            for (int r = 0; r < RR; ++r) {
                const float4 qa = *(const float4*)&qs[r * HD + c * 8];
                const float4 qb = *(const float4*)&qs[r * HD + c * 8 + 4];
                s[r] += qa.x * kf0 + qa.y * kf1 + qa.z * kf2 + qa.w * kf3
                      + qb.x * kf4 + qb.y * kf5 + qb.z * kf6 + qb.w * kf7;
            }
        }
        #pragma unroll
        for (int r = 0; r < RR; ++r) {
            bool keep = (j < RR) ? (j == r)
                                 : (mask[(size_t)(b * RR + r) * (Nn - RR) + (j - RR)] != 0);
            Ps[r][tid] = keep ? s[r] : -INFINITY;
        }
    }
    __syncthreads();

    // phase A2: per-row chunk max & exp-sum
    {
        const int r = tid >> 5, g = tid & 31;
        float vals[CK / 32];
        float mx = -INFINITY;
        #pragma unroll
        for (int i = 0; i < CK / 32; ++i) {
            vals[i] = Ps[r][g + 32 * i];
            mx = fmaxf(mx, vals[i]);
        }
        #pragma unroll
        for (int m = 16; m >= 1; m >>= 1) mx = fmaxf(mx, __shfl_xor(mx, m));
        const float mfin = fmaxf(mx, -1e30f);
        float sum = 0.f;
        #pragma unroll
        for (int i = 0; i < CK / 32; ++i) {
            float e = __expf(vals[i] - mfin);
            Ps[r][g + 32 * i] = e;
            sum += e;
        }
        #pragma unroll
        for (int m = 16; m >= 1; m >>= 1) sum += __shfl_xor(sum, m);
        if (g == 0) {
            size_t si = ((size_t)bh * NCHUNK + chunk) * RR + r;
            mstat[si] = mx;
            lstat[si] = sum;
        }
    }
    __syncthreads();

    // phase B: o[r,d] = sum_k P[r,k] * V[k,d]; 16 lanes x 4 dims, k split over 2 half-groups
    {
        const int r  = tid >> 5;
        const int g  = tid & 31;
        const int kh = g >> 4;               // 0/1 -> keys [kh*128, kh*128+128)
        const int d4 = (g & 15) * 4;
        float a0 = 0.f, a1 = 0.f, a2 = 0.f, a3 = 0.f;
        const float* pr = &Ps[r][kh * 128];
        const u16* vb = Vs + kh * 128 * HD + d4;
        #pragma unroll 2
        for (int k4 = 0; k4 < 32; ++k4) {
            f32x4 pv = *(const f32x4*)(pr + k4 * 4);
            #pragma unroll
            for (int t = 0; t < 4; ++t) {
                float p = pv[t];
                u32x2 vv = *(const u32x2*)(vb + (k4 * 4 + t) * HD);
                a0 += p * bflo(vv.x); a1 += p * bfhi(vv.x);
                a2 += p * bflo(vv.y); a3 += p * bfhi(vv.y);
            }
        }
        a0 += __shfl_xor(a0, 16); a1 += __shfl_xor(a1, 16);
        a2 += __shfl_xor(a2, 16); a3 += __shfl_xor(a3, 16);
        if (kh == 0) {
            size_t po = ((size_t)bh * NCHUNK + chunk) * (RR * HD) + r * HD + d4;
            float4 o = {a0, a1, a2, a3};
            *(float4*)(opart + po) = o;
        }
    }
}

// ---------------- combine partials -> f32 attention output ----------------
__global__ __launch_bounds__(256)
void attn_combine_kernel(const float* __restrict__ opart, const float* __restrict__ mstat,
                         const float* __restrict__ lstat, float* __restrict__ aob)
{
    int idx = blockIdx.x * 256 + threadIdx.x;   // < 64*1536
    int row = idx / Cc, col = idx - row * Cc;
    int b = row >> 3, r = row & 7;
    int h = col >> 6, d = col & 63;
    int bh = b * Hh + h;
    float M = -INFINITY;
    #pragma unroll
    for (int c = 0; c < NCHUNK; ++c)
        M = fmaxf(M, mstat[((size_t)bh * NCHUNK + c) * RR + r]);
    float L = 0.f, O = 0.f;
    #pragma unroll
    for (int c = 0; c < NCHUNK; ++c) {
        size_t si = ((size_t)bh * NCHUNK + c) * RR + r;
        float w = __expf(mstat[si] - M);
        L += w * lstat[si];
        O += w * opart[((size_t)bh * NCHUNK + c) * (RR * HD) + r * HD + d];
    }
    aob[(size_t)row * Cc + col] = O / L;
}

// ---------------- launch ----------------
extern "C" void kernel_launch(void* const* d_in, const int* in_sizes, int n_in,
                              void* d_out, int out_size, void* d_ws, size_t ws_size,
                              hipStream_t stream)
{
    const float* x    = (const float*)d_in[0];
    const int*   mask = (const int*)d_in[1];
    const float* Wq   = (const float*)d_in[2];
    const float* Wk   = (const float*)d_in[3];
    const float* Wv   = (const float*)d_in[4];
    const float* Wp   = (const float*)d_in[5];
    const float* bp   = (const float*)d_in[6];

    char* ws = (char*)d_ws;
    u16*   wkvb  = (u16*)(ws);                        //   9,437,184  [Wk;Wv] bf16 [3072,1536]
    u16*   wqb   = (u16*)(ws + 9437184);              //   4,718,592  Wq bf16
    u16*   wpb   = (u16*)(ws + 14155776);             //   4,718,592  Wp bf16
    u16*   kvb   = (u16*)(ws + 18874368);             // 201,326,592  kv bf16 [32768,3072]
    float* xqp   = (float*)(ws + 220200960);          //     786,432  q input padded [128,1536] f32
    float* qout  = (float*)(ws + 220987392);          //     786,432  q proj f32 [128,1536]
    float* aob   = (float*)(ws + 221773824);          //     786,432  attn out padded [128,1536] f32
    float* opart = (float*)(ws + 222560256);          //   6,291,456  [192][16][8][64] f32
    float* mstat = (float*)(ws + 228851712);          //      98,304
    float* lstat = (float*)(ws + 228950016);          //      98,304

    // 1: weight casts + q gather + zero fills
    prep_kernel<<<9696, 256, 0, stream>>>(x, Wk, Wv, Wq, Wp, wkvb, wqb, wpb,
                                          xqp, aob, (float*)d_out);
    // 2: q proj (blocks 0..11, A=xqp f32) + fused K/V proj (blocks 12..6155, A=x f32)
    gemm_main<<<6156, 256, 0, stream>>>(xqp, wqb, qout, x, wkvb, kvb);
    // 3: split attention
    attn_part_kernel<<<dim3(NCHUNK, Bb * Hh), 256, 0, stream>>>(qout, kvb, mask,
                                                                opart, mstat, lstat);
    // 4: combine (f32 out)
    attn_combine_kernel<<<384, 256, 0, stream>>>(opart, mstat, lstat, aob);
    // 5: output projection, split-K atomics (d_out zeroed by prep)
    gemm_out<<<dim3(12, 4), 256, 0, stream>>>(aob, wpb, (float*)d_out, bp);
}

// Round 6
// 849.012 us; speedup vs baseline: 1.0786x; 1.0756x over previous
//
#include <hip/hip_runtime.h>
#include <hip/hip_bf16.h>
#include <math.h>

// Problem constants (AttentionPool): B=8, N=4096, C=1536, H=24, hd=64, R=8
#define Bb 8
#define Nn 4096
#define Cc 1536
#define Hh 24
#define HD 64
#define RR 8
#define MKV (Bb * Nn)        // 32768 rows for K/V GEMM
#define NKV (2 * Cc)         // 3072 cols (K and V fused)
#define NCHUNK 16            // key chunks for split attention
#define CK 256               // keys per chunk

typedef unsigned short u16;
typedef unsigned int u32;
typedef __attribute__((ext_vector_type(2))) u32 u32x2;

typedef __attribute__((ext_vector_type(8))) short bf16x8;
typedef __attribute__((ext_vector_type(4))) float f32x4;

__device__ __forceinline__ u16 f32_to_bf16(float f) {
    union { float f; u32 u; } v; v.f = f;
    u32 r = v.u + 0x7fffu + ((v.u >> 16) & 1u);  // RNE
    return (u16)(r >> 16);
}
__device__ __forceinline__ float bflo(u32 p) {
    union { u32 u; float f; } v; v.u = p << 16; return v.f;
}
__device__ __forceinline__ float bfhi(u32 p) {
    union { u32 u; float f; } v; v.u = p & 0xffff0000u; return v.f;
}
__device__ __forceinline__ ushort4 cvt4(float4 v, float s) {
    ushort4 o;
    o.x = f32_to_bf16(v.x * s); o.y = f32_to_bf16(v.y * s);
    o.z = f32_to_bf16(v.z * s); o.w = f32_to_bf16(v.w * s);
    return o;
}

// ---------------- fused prep: casts + q gather + zero fills, one dispatch ----------------
// sections: [0,49152) x-cast+gather | [49152,58368) 4 weights | [58368,58464) zero xqp hi
//           [58464,58656) zero aob | [58656,58752) zero d_out
__global__ __launch_bounds__(256)
void prep_kernel(const float* __restrict__ x,
                 const float* __restrict__ Wk, const float* __restrict__ Wv,
                 const float* __restrict__ Wq, const float* __restrict__ Wp,
                 u16* __restrict__ xb, u16* __restrict__ wkvb,
                 u16* __restrict__ wqb, u16* __restrict__ wpb,
                 u16* __restrict__ xqp, u16* __restrict__ aob,
                 float* __restrict__ dout)
{
    const int blk = blockIdx.x, tid = threadIdx.x;
    if (blk < 49152) {
        int i = blk * 256 + tid;                 // quad index < 12582912
        float4 v = ((const float4*)x)[i];
        ((ushort4*)xb)[i] = cvt4(v, 1.0f);
        int row = i / 384;                       // 384 quads per 1536-row
        int n = row & (Nn - 1);
        if (n < RR) {                            // q gather, SCALE=0.125 folded (exact)
            int b = row >> 12;
            int cq = i - row * 384;
            ((ushort4*)xqp)[(size_t)(b * RR + n) * 384 + cq] = cvt4(v, 0.125f);
        }
    } else if (blk < 58368) {
        int t = blk - 49152;
        int w = t / 2304;
        int i = (t - w * 2304) * 256 + tid;      // < 589824 quads
        const float4* src = (w == 0) ? (const float4*)Wk : (w == 1) ? (const float4*)Wv
                          : (w == 2) ? (const float4*)Wq : (const float4*)Wp;
        u16* dst = (w == 0) ? wkvb : (w == 1) ? wkvb + 2359296 : (w == 2) ? wqb : wpb;
        ((ushort4*)dst)[i] = cvt4(src[i], 1.0f);
    } else if (blk < 58464) {                    // zero xqp rows 64..127
        int i = (blk - 58368) * 256 + tid;
        ushort4 z = {0, 0, 0, 0};
        ((ushort4*)(xqp + 64 * Cc))[i] = z;
    } else if (blk < 58656) {                    // zero aob (all 128 rows)
        int i = (blk - 58464) * 256 + tid;
        ushort4 z = {0, 0, 0, 0};
        ((ushort4*)aob)[i] = z;
    } else {                                     // zero d_out (for split-K atomics)
        int i = (blk - 58656) * 256 + tid;
        float4 z = {0.f, 0.f, 0.f, 0.f};
        ((float4*)dout)[i] = z;
    }
}

// ---------------- GEMM body: 128x128 tile, BK=64, XOR-swizzled LDS (round-3, 0 conflicts) ----
// C[M,N] = A[M,K] * B[N,K]^T.  LDS row = 64 elems (128 B); chunk = 8 elems (16 B);
// chunk c of row r stored at c ^ (r&7).
// OUT: 0 = f32 store, 1 = bf16 store, 2 = f32 atomicAdd (split-K)
template <int OUT>
__device__ __forceinline__ void gemm_body64(
    const u16* __restrict__ A, const u16* __restrict__ B, void* __restrict__ Cv,
    const float* __restrict__ bias, int M_valid, int N, int K,
    int m0, int n0, int kbeg, int kend, u16* As, u16* Bs)
{
    const int tid = threadIdx.x;
    const int wave = tid >> 6, lane = tid & 63;
    const int wm = (wave & 1) * 64, wn = (wave >> 1) * 64;
    const int fm = lane & 15;
    const int kq = lane >> 4;            // 0..3

    f32x4 acc[4][4] = {};

    // staging: LDS slot e = tid*8 + off*2048 elems; r=e>>6, c'=(e>>3)&7; src chunk c'^(r&7)
    const u16* aptr[4]; const u16* bptr[4]; int ldsoff[4];
    #pragma unroll
    for (int off = 0; off < 4; ++off) {
        int e = tid * 8 + off * 2048;
        int r = e >> 6, cp = (e >> 3) & 7;
        int csrc = cp ^ (r & 7);
        aptr[off] = A + (size_t)(m0 + r) * K + csrc * 8;
        bptr[off] = B + (size_t)(n0 + r) * K + csrc * 8;
        ldsoff[off] = e;
    }

    for (int k0 = kbeg; k0 < kend; k0 += 64) {
        #pragma unroll
        for (int off = 0; off < 4; ++off)
            __builtin_amdgcn_global_load_lds(
                (const __attribute__((address_space(1))) void*)(aptr[off] + k0),
                (__attribute__((address_space(3))) void*)(As + ldsoff[off]), 16, 0, 0);
        #pragma unroll
        for (int off = 0; off < 4; ++off)
            __builtin_amdgcn_global_load_lds(
                (const __attribute__((address_space(1))) void*)(bptr[off] + k0),
                (__attribute__((address_space(3))) void*)(Bs + ldsoff[off]), 16, 0, 0);
        __syncthreads();

        #pragma unroll
        for (int ks = 0; ks < 2; ++ks) {
            bf16x8 af[4], bfr[4];
            #pragma unroll
            for (int i = 0; i < 4; ++i) {
                int r = wm + i * 16 + fm;
                int c = ks * 4 + kq;
                af[i] = *(const bf16x8*)&As[r * 64 + ((c ^ (r & 7)) << 3)];
            }
            #pragma unroll
            for (int j = 0; j < 4; ++j) {
                int r = wn + j * 16 + fm;
                int c = ks * 4 + kq;
                bfr[j] = *(const bf16x8*)&Bs[r * 64 + ((c ^ (r & 7)) << 3)];
            }
            #pragma unroll
            for (int i = 0; i < 4; ++i)
                #pragma unroll
                for (int j = 0; j < 4; ++j)
                    acc[i][j] = __builtin_amdgcn_mfma_f32_16x16x32_bf16(af[i], bfr[j], acc[i][j], 0, 0, 0);
        }
        __syncthreads();
    }

    // C/D layout: col = lane&15, row = (lane>>4)*4 + reg  [m89, verified]
    const int col = lane & 15, rb = (lane >> 4) * 4;
    #pragma unroll
    for (int i = 0; i < 4; ++i)
        #pragma unroll
        for (int j = 0; j < 4; ++j)
            #pragma unroll
            for (int rg = 0; rg < 4; ++rg) {
                int m = m0 + wm + i * 16 + rb + rg;
                if (m < M_valid) {
                    int n = n0 + wn + j * 16 + col;
                    float v = acc[i][j][rg];
                    if (bias) v += bias[n];
                    size_t idx = (size_t)m * N + n;
                    if (OUT == 0)       ((float*)Cv)[idx] = v;
                    else if (OUT == 1)  ((u16*)Cv)[idx] = f32_to_bf16(v);
                    else                atomicAdd((float*)Cv + idx, v);
                }
            }
}

// ---------------- merged dispatch: blocks 0..11 = q proj; 12..6155 = KV proj ----------------
// KV decode XCD-aware: class g = u&7 owns m-tiles [g*32, g*32+32), n fastest.
__global__ __launch_bounds__(256, 3)
void gemm_main(const u16* __restrict__ xqp, const u16* __restrict__ wqb,
               float* __restrict__ qout,
               const u16* __restrict__ xb, const u16* __restrict__ wkvb,
               u16* __restrict__ kvb)
{
    __shared__ u16 As[128 * 64];
    __shared__ u16 Bs[128 * 64];
    const int blk = blockIdx.x;
    if (blk < 12) {
        gemm_body64<0>(xqp, wqb, qout, nullptr, 64, Cc, Cc, 0, blk * 128, 0, Cc, As, Bs);
    } else {
        int u = blk - 12;
        int g = u & 7, s = u >> 3;               // 768 blocks per XCD class
        int mb = g * 32 + s / 24, nb = s % 24;
        gemm_body64<1>(xb, wkvb, kvb, nullptr, MKV, NKV, Cc, mb * 128, nb * 128, 0, Cc, As, Bs);
    }
}

// ---------------- output projection, split-K x4 with f32 atomics ----------------
__global__ __launch_bounds__(256, 3)
void gemm_out(const u16* __restrict__ aob, const u16* __restrict__ wpb,
              float* __restrict__ out, const float* __restrict__ bp)
{
    __shared__ u16 As[128 * 64];
    __shared__ u16 Bs[128 * 64];
    const int nb = blockIdx.x;                   // 0..11
    const int z = blockIdx.y;                    // 0..3
    gemm_body64<2>(aob, wpb, out, (z == 0) ? bp : nullptr,
                   64, Cc, Cc, 0, nb * 128, z * 384, (z + 1) * 384, As, Bs);
}

// ---------------- split attention: grid (NCHUNK, B*H), 256 keys per block ----------------
__global__ __launch_bounds__(256)
void attn_part_kernel(const float* __restrict__ qout, const u16* __restrict__ kv,
                      const int* __restrict__ mask,
                      float* __restrict__ opart, float* __restrict__ mstat,
                      float* __restrict__ lstat)
{
    const int chunk = blockIdx.x;       // 0..15
    const int bh = blockIdx.y;          // 0..191
    const int b = bh / Hh, h = bh - b * Hh;
    const int tid = threadIdx.x;

    __shared__ u16  Vs[CK * HD];        // 32 KB
    __shared__ float Ps[RR][CK];        // 8 KB
    __shared__ float qs[RR * HD];       // 2 KB

    for (int i = tid; i < RR * HD; i += 256)
        qs[i] = qout[(size_t)(b * RR + (i >> 6)) * Cc + h * HD + (i & 63)];
    __syncthreads();

    // V-chunk DMA (overlaps QK^T; drained by the next barrier)
    {
        const u16* vsrc = kv + (size_t)(b * Nn + chunk * CK) * NKV + Cc + h * HD;
        const int vr = tid >> 3, vc = (tid & 7) * 8;
        #pragma unroll
        for (int i = 0; i < 8; ++i) {
            __builtin_amdgcn_global_load_lds(
                (const __attribute__((address_space(1))) void*)(vsrc + (size_t)(i * 32 + vr) * NKV + vc),
                (__attribute__((address_space(3))) void*)(Vs + i * 2048 + tid * 8), 16, 0, 0);
        }
    }

    // phase A: thread = key; masked scores
    {
        const int j = chunk * CK + tid;
        float s[RR] = {0, 0, 0, 0, 0, 0, 0, 0};
        const u16* krow = kv + (size_t)(b * Nn + j) * NKV + h * HD;
        #pragma unroll
        for (int c = 0; c < 8; ++c) {
            uint4 kvec = *(const uint4*)(krow + c * 8);
            float kf0 = bflo(kvec.x), kf1 = bfhi(kvec.x);
            float kf2 = bflo(kvec.y), kf3 = bfhi(kvec.y);
            float kf4 = bflo(kvec.z), kf5 = bfhi(kvec.z);
            float kf6 = bflo(kvec.w), kf7 = bfhi(kvec.w);
            #pragma unroll
            for (int r = 0; r < RR; ++r) {
                const float4 qa = *(const float4*)&qs[r * HD + c * 8];
                const float4 qb = *(const float4*)&qs[r * HD + c * 8 + 4];
                s[r] += qa.x * kf0 + qa.y * kf1 + qa.z * kf2 + qa.w * kf3
                      + qb.x * kf4 + qb.y * kf5 + qb.z * kf6 + qb.w * kf7;
            }
        }
        #pragma unroll
        for (int r = 0; r < RR; ++r) {
            bool keep = (j < RR) ? (j == r)
                                 : (mask[(size_t)(b * RR + r) * (Nn - RR) + (j - RR)] != 0);
            Ps[r][tid] = keep ? s[r] : -INFINITY;
        }
    }
    __syncthreads();

    // phase A2: per-row chunk max & exp-sum
    {
        const int r = tid >> 5, g = tid & 31;
        float vals[CK / 32];
        float mx = -INFINITY;
        #pragma unroll
        for (int i = 0; i < CK / 32; ++i) {
            vals[i] = Ps[r][g + 32 * i];
            mx = fmaxf(mx, vals[i]);
        }
        #pragma unroll
        for (int m = 16; m >= 1; m >>= 1) mx = fmaxf(mx, __shfl_xor(mx, m));
        const float mfin = fmaxf(mx, -1e30f);
        float sum = 0.f;
        #pragma unroll
        for (int i = 0; i < CK / 32; ++i) {
            float e = __expf(vals[i] - mfin);
            Ps[r][g + 32 * i] = e;
            sum += e;
        }
        #pragma unroll
        for (int m = 16; m >= 1; m >>= 1) sum += __shfl_xor(sum, m);
        if (g == 0) {
            size_t si = ((size_t)bh * NCHUNK + chunk) * RR + r;
            mstat[si] = mx;
            lstat[si] = sum;
        }
    }
    __syncthreads();

    // phase B: o[r,d] = sum_k P[r,k] * V[k,d]; 16 lanes x 4 dims, k split over 2 half-groups
    {
        const int r  = tid >> 5;
        const int g  = tid & 31;
        const int kh = g >> 4;               // 0/1 -> keys [kh*128, kh*128+128)
        const int d4 = (g & 15) * 4;
        float a0 = 0.f, a1 = 0.f, a2 = 0.f, a3 = 0.f;
        const float* pr = &Ps[r][kh * 128];
        const u16* vb = Vs + kh * 128 * HD + d4;
        #pragma unroll 2
        for (int k4 = 0; k4 < 32; ++k4) {
            f32x4 pv = *(const f32x4*)(pr + k4 * 4);
            #pragma unroll
            for (int t = 0; t < 4; ++t) {
                float p = pv[t];
                u32x2 vv = *(const u32x2*)(vb + (k4 * 4 + t) * HD);
                a0 += p * bflo(vv.x); a1 += p * bfhi(vv.x);
                a2 += p * bflo(vv.y); a3 += p * bfhi(vv.y);
            }
        }
        a0 += __shfl_xor(a0, 16); a1 += __shfl_xor(a1, 16);
        a2 += __shfl_xor(a2, 16); a3 += __shfl_xor(a3, 16);
        if (kh == 0) {
            size_t po = ((size_t)bh * NCHUNK + chunk) * (RR * HD) + r * HD + d4;
            float4 o = {a0, a1, a2, a3};
            *(float4*)(opart + po) = o;
        }
    }
}

// ---------------- combine partials -> bf16 attention output ----------------
__global__ __launch_bounds__(256)
void attn_combine_kernel(const float* __restrict__ opart, const float* __restrict__ mstat,
                         const float* __restrict__ lstat, u16* __restrict__ aob)
{
    int idx = blockIdx.x * 256 + threadIdx.x;   // < 64*1536
    int row = idx / Cc, col = idx - row * Cc;
    int b = row >> 3, r = row & 7;
    int h = col >> 6, d = col & 63;
    int bh = b * Hh + h;
    float M = -INFINITY;
    #pragma unroll
    for (int c = 0; c < NCHUNK; ++c)
        M = fmaxf(M, mstat[((size_t)bh * NCHUNK + c) * RR + r]);
    float L = 0.f, O = 0.f;
    #pragma unroll
    for (int c = 0; c < NCHUNK; ++c) {
        size_t si = ((size_t)bh * NCHUNK + c) * RR + r;
        float w = __expf(mstat[si] - M);
        L += w * lstat[si];
        O += w * opart[((size_t)bh * NCHUNK + c) * (RR * HD) + r * HD + d];
    }
    aob[(size_t)row * Cc + col] = f32_to_bf16(O / L);
}

// ---------------- launch ----------------
extern "C" void kernel_launch(void* const* d_in, const int* in_sizes, int n_in,
                              void* d_out, int out_size, void* d_ws, size_t ws_size,
                              hipStream_t stream)
{
    const float* x    = (const float*)d_in[0];
    const int*   mask = (const int*)d_in[1];
    const float* Wq   = (const float*)d_in[2];
    const float* Wk   = (const float*)d_in[3];
    const float* Wv   = (const float*)d_in[4];
    const float* Wp   = (const float*)d_in[5];
    const float* bp   = (const float*)d_in[6];

    char* ws = (char*)d_ws;
    u16*   xb     = (u16*)(ws);                       // 100,663,296  x bf16 [32768,1536]
    u16*   wkvb   = (u16*)(ws + 100663296);           //   9,437,184  [Wk;Wv] bf16 [3072,1536]
    u16*   wqb    = (u16*)(ws + 110100480);           //   4,718,592  Wq bf16
    u16*   wpb    = (u16*)(ws + 114819072);           //   4,718,592  Wp bf16
    u16*   kvb    = (u16*)(ws + 119537664);           // 201,326,592  kv bf16 [32768,3072]
    u16*   xqp    = (u16*)(ws + 320864256);           //     393,216  q input padded [128,1536]
    float* qout   = (float*)(ws + 321257472);         //     786,432  q proj f32 [128,1536]
    u16*   aob    = (u16*)(ws + 322043904);           //     393,216  attn out padded [128,1536]
    // partials alias xb (dead after KV GEMM)
    float* opart  = (float*)(ws);                     // 6,291,456 B
    float* mstat  = (float*)(ws + 6291456);           // 98,304 B
    float* lstat  = (float*)(ws + 6389760);           // 98,304 B

    // 1: all casts + q gather + zero fills
    prep_kernel<<<58752, 256, 0, stream>>>(x, Wk, Wv, Wq, Wp, xb, wkvb, wqb, wpb,
                                           xqp, aob, (float*)d_out);
    // 2: q proj (blocks 0..11) + fused K/V proj (blocks 12..6155)
    gemm_main<<<6156, 256, 0, stream>>>(xqp, wqb, qout, xb, wkvb, kvb);
    // 3: split attention
    attn_part_kernel<<<dim3(NCHUNK, Bb * Hh), 256, 0, stream>>>(qout, kvb, mask,
                                                                opart, mstat, lstat);
    // 4: combine
    attn_combine_kernel<<<384, 256, 0, stream>>>(opart, mstat, lstat, aob);
    // 5: output projection, split-K atomics (d_out zeroed by prep)
    gemm_out<<<dim3(12, 4), 256, 0, stream>>>(aob, wpb, (float*)d_out, bp);
}